// Round 10
// baseline (220.452 us; speedup 1.0000x reference)
//
#include <hip/hip_runtime.h>

// Problem dims (fixed by setup_inputs)
constexpr int Bc = 4, Cc = 128, Hc = 192, Wc = 192;
constexpr int HI = 96, WI = 96;       // half-res inputs
constexpr int NB = 64;                // n_bins
constexpr int NA = 16;                // n_att
constexpr float SCL = 95.0f / 191.0f; // align_corners scale (96->192)

typedef __attribute__((ext_vector_type(8))) short bf16x8;
typedef __attribute__((ext_vector_type(4))) float f32x4;

__device__ __forceinline__ unsigned short f2bf(float f) {
  unsigned u = __builtin_bit_cast(unsigned, f);
  unsigned r = (u + 0x7FFFu + ((u >> 16) & 1u)) >> 16;   // RNE
  return (unsigned short)r;
}
__device__ __forceinline__ float rcp_fast(float r) {
#if defined(__has_builtin)
#if __has_builtin(__builtin_amdgcn_rcpf)
  return __builtin_amdgcn_rcpf(r);
#else
  return 1.0f / r;
#endif
#else
  return 1.0f / r;
#endif
}

// ---------------------------------------------------------------------------
// K1 (MFMA). One block per (b, y, 64-px x-tile). 256 threads = 4 waves.
// R8: k_prep folded in. Each block gathers its w1 fragments directly from
// the f32 w1 (16B loads at fragment addresses; w1=64KB -> L2-resident after
// the first blocks), converts in-register (same RNE f2bf as k_prep did),
// and writes LDS frag-linear via ds_write_b128 (conflict-free). w2/b2 read
// directly too. Pipeline is now 2 dispatches; ws holds only att.
// Lessons ledger: (256,8)->VGPR 32 spill [R1]; 81920B LDS -> 1 blk/CU [R4];
// (256,4)+two-pass -> VGPR-64 spill [R5]; (256,3) proven: 51.7KB LDS,
// 3 blk/CU, VGPR cap 170, <52us.
// ---------------------------------------------------------------------------
__global__ __launch_bounds__(256, 3) void k_att(
    const float* __restrict__ x, const float* __restrict__ pbe,
    const float* __restrict__ w1, const float* __restrict__ b1,
    const float* __restrict__ w2, const float* __restrict__ b2,
    float* __restrict__ att)
{
  constexpr int PH = 136;   // a1_s pitch (bf16)
  constexpr int RP = 37;    // row_s pitch (f32), odd
  __shared__ __align__(16) unsigned char smem[32768 + 128 * RP * 4];
  unsigned short* w1_s  = (unsigned short*)smem;                // frag-linear
  float*          row_s = (float*)(smem + 32768);               // [128][37]
  unsigned short* a1_s  = (unsigned short*)(smem + 32768);      // [64][136]

  const int tid = threadIdx.x;
  const int xg0 = blockIdx.x * 64;
  const int y = blockIdx.y;
  const int b = blockIdx.z;

  const float ysf = y * SCL;
  const int y0 = (int)ysf;
  const int y1 = min(y0 + 1, HI - 1);
  const float wy = ysf - (float)y0;
  const int xi0 = (int)(xg0 * SCL);

  const int lane = tid & 63;
  const int wv = tid >> 6;        // wave id 0..3
  const int ln = lane & 15;
  const int qd = lane >> 4;
  const int m0 = wv * 16;

  const int xg = xg0 + m0 + ln;
  const float xsf = (float)xg * SCL;
  const int x0i = (int)xsf;
  const float wx = xsf - (float)x0i;
  const int xl = x0i - xi0;             // 0..32, xl+1 <= 33

  // ---- w1 fragment gather (global f32 -> reg), issued first.
  // fragment f = tid+256*i: nt=f>>8, kt=(f>>6)&3, l=f&63;
  // covers w1[n=nt*16+(l&15)][k0=kt*32+(l>>4)*8 .. +7] as two float4.
  float4 fA[8], fB[8];
  #pragma unroll
  for (int i = 0; i < 8; ++i) {
    const int f = tid + 256 * i;
    const int nt = f >> 8;
    const int kt = (f >> 6) & 3;
    const int l  = f & 63;
    const float* wr = w1 + (nt * 16 + (l & 15)) * 128 + kt * 32 + (l >> 4) * 8;
    fA[i] = *(const float4*)wr;
    fB[i] = *(const float4*)(wr + 4);
  }

  // ---- w2 even-row fragments (direct, L2-hot) + biases
  bf16x8 b2f[4];
  #pragma unroll
  for (int kt = 0; kt < 4; ++kt) {
    const float* wr = w2 + (2 * ln) * 128 + kt * 32 + qd * 8;
    const float4 a = *(const float4*)wr;
    const float4 c = *(const float4*)(wr + 4);
    bf16x8 fr;
    fr[0] = (short)f2bf(a.x); fr[1] = (short)f2bf(a.y);
    fr[2] = (short)f2bf(a.z); fr[3] = (short)f2bf(a.w);
    fr[4] = (short)f2bf(c.x); fr[5] = (short)f2bf(c.y);
    fr[6] = (short)f2bf(c.z); fr[7] = (short)f2bf(c.w);
    b2f[kt] = fr;
  }
  float bias1[8];
  #pragma unroll
  for (int nt = 0; nt < 8; ++nt) bias1[nt] = b1[nt * 16 + ln];
  const float bias2 = b2[2 * ln];

  // ---- hoisted x loads: xr[kt*8+j] = x[c = kt*32+qd*8+j][y][xg]
  float xr[32];
  #pragma unroll
  for (int kt = 0; kt < 4; ++kt) {
    #pragma unroll
    for (int j = 0; j < 8; ++j) {
      const int c = kt * 32 + qd * 8 + j;
      xr[kt * 8 + j] = x[((size_t)(b * Cc + c) * Hc + y) * Wc + xg];
    }
  }

  // ---- phase 1: row_s[c][xi] = y-interp of pbe (coalesced loads, f32)
  #pragma unroll
  for (int i = 0; i < 18; ++i) {
    const int f = tid + 256 * i;        // 0..4607
    const int c = f / 36;
    const int xi = f - c * 36;
    const int xgl = min(xi0 + xi, WI - 1);
    const float* p = pbe + (size_t)(b * Cc + c) * (HI * WI);
    const float top = p[y0 * WI + xgl];
    const float bot = p[y1 * WI + xgl];
    row_s[c * RP + xi] = top + wy * (bot - top);
  }

  // ---- w1 fragments: cvt + LDS write (ds_write_b128, linear, conflict-free)
  #pragma unroll
  for (int i = 0; i < 8; ++i) {
    bf16x8 fr;
    fr[0] = (short)f2bf(fA[i].x); fr[1] = (short)f2bf(fA[i].y);
    fr[2] = (short)f2bf(fA[i].z); fr[3] = (short)f2bf(fA[i].w);
    fr[4] = (short)f2bf(fB[i].x); fr[5] = (short)f2bf(fB[i].y);
    fr[6] = (short)f2bf(fB[i].z); fr[7] = (short)f2bf(fB[i].w);
    *(bf16x8*)&w1_s[(size_t)(tid + 256 * i) * 8] = fr;
  }
  __syncthreads();

  // ---- build A-fragments in registers from xr + row_s
  bf16x8 af[4];
  #pragma unroll
  for (int kt = 0; kt < 4; ++kt) {
    #pragma unroll
    for (int j = 0; j < 8; ++j) {
      const int c = kt * 32 + qd * 8 + j;
      const float v0 = row_s[c * RP + xl];
      const float v1 = row_s[c * RP + xl + 1];
      af[kt][j] = (short)f2bf(xr[kt * 8 + j] + v0 + wx * (v1 - v0));
    }
  }
  __syncthreads();   // row_s dead -> region reusable as a1_s

  // ---- GEMM1: C[64m][128n] = h[64m][128k] * w1[128n][128k]^T (B from LDS)
  f32x4 acc[8];
  #pragma unroll
  for (int nt = 0; nt < 8; ++nt) acc[nt] = f32x4{0.f, 0.f, 0.f, 0.f};
  #pragma unroll
  for (int nt = 0; nt < 8; ++nt) {
    #pragma unroll
    for (int kt = 0; kt < 4; ++kt) {
      const bf16x8 bf = *(const bf16x8*)&w1_s[(nt * 4 + kt) * 512 + lane * 8];
      acc[nt] = __builtin_amdgcn_mfma_f32_16x16x32_bf16(af[kt], bf, acc[nt], 0, 0, 0);
    }
  }

  // epilogue: relu(+bias) -> a1_s (bf16). Wave writes only its own 16 rows.
  #pragma unroll
  for (int nt = 0; nt < 8; ++nt) {
    const int n = nt * 16 + ln;
    const float bias = bias1[nt];
    #pragma unroll
    for (int r = 0; r < 4; ++r) {
      const int m = m0 + qd * 4 + r;
      a1_s[m * PH + n] = f2bf(fmaxf(acc[nt][r] + bias, 0.f));
    }
  }
  // no __syncthreads: each wave reads back only rows it wrote

  // ---- GEMM2: att[64m][16j] = a1[64m][128k] * w2e[16j][128k]^T
  f32x4 acc2 = f32x4{0.f, 0.f, 0.f, 0.f};
  #pragma unroll
  for (int kt = 0; kt < 4; ++kt) {
    const bf16x8 a2 = *(const bf16x8*)&a1_s[(m0 + ln) * PH + kt * 32 + qd * 8];
    acc2 = __builtin_amdgcn_mfma_f32_16x16x32_bf16(a2, b2f[kt], acc2, 0, 0, 0);
  }
  #pragma unroll
  for (int r = 0; r < 4; ++r) {
    const int opx = m0 + qd * 4 + r;
    const float v = fmaxf(acc2[r] + bias2, 0.f) + 0.001f;
    att[((size_t)((b * Hc + y) * Wc) + xg0 + opx) * NA + ln] = v;
  }
}

// ---------------------------------------------------------------------------
// K2: block = one image row, 384 threads = 192 px x 2 bin-halves.
// R8: EXACT R3 restore — empirical best (50us, VGPR 52, 0 conflicts).
// R7's half-row split at (192,4) came out VGPR 36 < the ~52-reg working set
// (v[32]+am[16]) -> L2-resident scratch spill, 53us; reverted.
// ---------------------------------------------------------------------------
__global__ __launch_bounds__(384, 4) void k_bins(
    const float* __restrict__ pb, const float* __restrict__ att,
    float* __restrict__ out0, float* __restrict__ out1)
{
  __shared__ __align__(16) float row_s[NB][WI];   // 24576 B; aliased as xch
  float* xch = &row_s[0][0];                      // [32][192] after delta

  const int tid = threadIdx.x;      // 0..383
  const int h = (tid >= 192) ? 1 : 0;   // bin half (wave-uniform)
  const int px = tid - 192 * h;         // pixel 0..191
  const int y = blockIdx.x;
  const int b = blockIdx.y;

  const float ysf = y * SCL;
  const int y0 = (int)ysf;
  const int y1 = min(y0 + 1, HI - 1);
  const float wy = ysf - (float)y0;

  // att for this pixel: 16 floats, contiguous — issue first (independent)
  float am[16];
  {
    const float4* ap = (const float4*)(att + ((size_t)((b * Hc + y) * Wc) + px) * NA);
    const float4 a0 = ap[0], a1 = ap[1], a2 = ap[2], a3 = ap[3];
    am[0] = a0.x;  am[1] = a0.y;  am[2] = a0.z;  am[3] = a0.w;
    am[4] = a1.x;  am[5] = a1.y;  am[6] = a1.z;  am[7] = a1.w;
    am[8] = a2.x;  am[9] = a2.y;  am[10] = a2.z; am[11] = a2.w;
    am[12] = a3.x; am[13] = a3.y; am[14] = a3.z; am[15] = a3.w;
  }

  // ---- stage y-interpolated pb rows for all 64 bins: 1536 float4 positions
  #pragma unroll
  for (int i = 0; i < 4; ++i) {
    const int u = tid + 384 * i;          // 0..1535
    const int k = u / 24;
    const int g = u - k * 24;             // float4 group in row
    const float* base = pb + (size_t)(b * NB + k) * (HI * WI);
    const float4 t4 = *(const float4*)&base[y0 * WI + g * 4];
    const float4 b4 = *(const float4*)&base[y1 * WI + g * 4];
    float4 r;
    r.x = t4.x + wy * (b4.x - t4.x);
    r.y = t4.y + wy * (b4.y - t4.y);
    r.z = t4.z + wy * (b4.z - t4.z);
    r.w = t4.w + wy * (b4.w - t4.w);
    *(float4*)&row_s[k][g * 4] = r;
  }
  __syncthreads();

  const float xsf = px * SCL;
  const int x0 = (int)xsf;          // <= 94
  const float wx = xsf - (float)x0;

  const size_t obase = (size_t)(b * NB) * (Hc * Wc) + (size_t)y * Wc + px;
  float v[32];                      // this thread's 32 bins (k = h*32 + i)

  // ---- delta: 4 bins in flight -> 4 independent rcp chains
  #pragma unroll
  for (int kb = 0; kb < 32; kb += 4) {
    float bc[4], dl[4];
    #pragma unroll
    for (int q = 0; q < 4; ++q) {
      const int k = h * 32 + kb + q;
      const float v0 = row_s[k][x0], v1 = row_s[k][x0 + 1];
      bc[q] = v0 + wx * (v1 - v0);
      dl[q] = 0.f;
    }
    #pragma unroll
    for (int j = 0; j < NA; ++j) {
      const float a = am[j];
      #pragma unroll
      for (int q = 0; q < 4; ++q) {
        const float d = a - bc[q];
        const float rq = fmaf(300.f * d, d, 1.f);
        dl[q] = fmaf(d, rcp_fast(rq), dl[q]);
      }
    }
    #pragma unroll
    for (int q = 0; q < 4; ++q) {
      const float bnc = fmaf(dl[q], 1.f / 16.f, bc[q]);
      out0[obase + (size_t)(h * 32 + kb + q) * (Hc * Wc)] = bnc;
      v[kb + q] = fmaf(9.999f, bnc, 0.001f);
    }
  }

  // ---- per-thread bitonic sort of 32: h0 ascending, h1 descending.
  // [h0 asc | h1 desc] forms a bitonic 64-sequence.
  if (h == 0) {
    #pragma unroll
    for (int size = 2; size <= 32; size <<= 1)
      #pragma unroll
      for (int stride = size >> 1; stride >= 1; stride >>= 1)
        #pragma unroll
        for (int i = 0; i < 32; ++i)
          if ((i & stride) == 0) {
            const int j = i | stride;
            const bool asc = ((i & size) == 0);
            const float a = v[i], c = v[j];
            const float lo = fminf(a, c), hi = fmaxf(a, c);
            v[i] = asc ? lo : hi;
            v[j] = asc ? hi : lo;
          }
  } else {
    #pragma unroll
    for (int size = 2; size <= 32; size <<= 1)
      #pragma unroll
      for (int stride = size >> 1; stride >= 1; stride >>= 1)
        #pragma unroll
        for (int i = 0; i < 32; ++i)
          if ((i & stride) == 0) {
            const int j = i | stride;
            const bool asc = ((i & size) != 0);   // descending overall
            const float a = v[i], c = v[j];
            const float lo = fminf(a, c), hi = fmaxf(a, c);
            v[i] = asc ? lo : hi;
            v[j] = asc ? hi : lo;
          }
  }

  // ---- cross-thread stride-32 CE layer through LDS (row_s is dead)
  __syncthreads();                       // all row_s reads done
  if (h) {
    #pragma unroll
    for (int i = 0; i < 32; ++i) xch[i * 192 + px] = v[i];
  }
  __syncthreads();
  if (!h) {
    #pragma unroll
    for (int i = 0; i < 32; ++i) {
      const float o = xch[i * 192 + px];
      const float mn = fminf(v[i], o), mx = fmaxf(v[i], o);
      v[i] = mn;
      xch[i * 192 + px] = mx;
    }
  }
  __syncthreads();
  if (h) {
    #pragma unroll
    for (int i = 0; i < 32; ++i) v[i] = xch[i * 192 + px];
  }

  // ---- each half is bitonic; 5 ascending merge layers finish the sort
  #pragma unroll
  for (int stride = 16; stride >= 1; stride >>= 1)
    #pragma unroll
    for (int i = 0; i < 32; ++i)
      if ((i & stride) == 0) {
        const int j = i | stride;
        const float a = v[i], c = v[j];
        v[i] = fminf(a, c);
        v[j] = fmaxf(a, c);
      }

  // h0 holds global ranks 0..31, h1 ranks 32..63
  #pragma unroll
  for (int i = 0; i < 32; ++i) {
    out1[obase + (size_t)(h * 32 + i) * (Hc * Wc)] =
        fminf(fmaxf(v[i], 0.001f), 10.0f);
  }
}

// ---------------------------------------------------------------------------
extern "C" void kernel_launch(void* const* d_in, const int* in_sizes, int n_in,
                              void* d_out, int out_size, void* d_ws, size_t ws_size,
                              hipStream_t stream) {
  const float* x   = (const float*)d_in[0];   // (4,128,192,192)
  const float* pb  = (const float*)d_in[1];   // (4,64,96,96)
  const float* pbe = (const float*)d_in[2];   // (4,128,96,96)
  const float* w1  = (const float*)d_in[3];   // (128,128)
  const float* b1  = (const float*)d_in[4];   // (128,)
  const float* w2  = (const float*)d_in[5];   // (32,128)
  const float* b2  = (const float*)d_in[6];   // (32,)

  float* out0 = (float*)d_out;                       // bin_new_centers
  float* out1 = out0 + (size_t)Bc * NB * Hc * Wc;    // bin_centers

  // ws layout: [att f32 9.4MB] — weight prepack eliminated (folded into k_att)
  float* att = (float*)d_ws;                         // [b][y][x][j]

  dim3 g1(Wc / 64, Hc, Bc);
  k_att<<<g1, 256, 0, stream>>>(x, pbe, w1, b1, w2, b2, att);

  dim3 g2(Hc, Bc);
  k_bins<<<g2, 384, 0, stream>>>(pb, att, out0, out1);
}